// Round 1
// baseline (586.584 us; speedup 1.0000x reference)
//
#include <hip/hip_runtime.h>

// ---------------------------------------------------------------------------
// SHCA: scaled cross-attention
//   xk = X@Xk_w.T + Xk_b            (2048*8, 512)
//   yq = Y@Yq_w.T + Yq_b            (1024*8, 512)
//   logit[b,y,x] = (yq.xk)/sqrt(512) + sigmoid(align_w)*alignment - mask*FMAX
//   attn = softmax_x(logit)
//   xv = X@Xv_w.T + Xv_b
//   attn_feat[y,b,h] = sum_x attn[b,y,x] xv[x,b,h]
//   out = concat(Y, attn_feat) @ Yw_w.T + Yw_b    (1024,8,1024) fp32
// All GEMMs via bf16 MFMA 16x16x32 (A x B^T form, both K-contiguous).
// ---------------------------------------------------------------------------

#define FMAXF 3.402823466e38f

typedef __attribute__((ext_vector_type(8))) __bf16 bf16x8;
typedef __attribute__((ext_vector_type(4))) float f32x4;

static __device__ __forceinline__ short f2b(float f) {
  union { float f; unsigned u; } x; x.f = f;
  unsigned r = (x.u + 0x7FFFu + ((x.u >> 16) & 1u)) >> 16;
  return (short)r;
}
static __device__ __forceinline__ float b2f(short s) {
  union { unsigned u; float f; } x; x.u = ((unsigned)(unsigned short)s) << 16;
  return x.f;
}

// ---------------- epilogue functors -----------------------------------------

// out[b][m>>3][n] bf16 (+bias), for xk (rowsPerB=2048) / yq (rowsPerB=1024);
// GEMM row m = x*8 + b.
struct EpiSplitBXD {
  short* out; const float* bias; int rowsPerB;
  __device__ void operator()(int bz, int m, int n, float v) const {
    v += bias[n];
    long idx = (((long)(m & 7)) * rowsPerB + (m >> 3)) * 512 + n;
    out[idx] = f2b(v);
  }
};

// xv stored transposed: out[b][n][x] bf16 (+bias); m = x*8+b, XLEN=2048, N=512
struct EpiXvt {
  short* out; const float* bias;
  __device__ void operator()(int bz, int m, int n, float v) const {
    v += bias[n];
    long idx = (((long)(m & 7)) * 512 + n) * 2048 + (m >> 3);
    out[idx] = f2b(v);
  }
};

// logits: scale, gated alignment, pad-mask fill; bf16 store [b][y][x]
struct EpiLogit {
  short* out; const float* align; const int* mask; const float* alw;
  __device__ void operator()(int bz, int m, int n, float v) const {
    long idx = ((long)bz * 1024 + m) * 2048 + n;
    float g = 1.0f / (1.0f + __expf(-alw[0]));
    v = v * 0.04419417382415922f + g * align[idx];   // 1/sqrt(512)
    if (mask[idx]) v = -FMAXF;
    out[idx] = f2b(v);
  }
};

// attn_feat -> concat[(y*8+b)][1024+n] bf16 (no bias)
struct EpiConcat {
  short* out;
  __device__ void operator()(int bz, int m, int n, float v) const {
    long row = (long)m * 8 + bz;
    out[row * 1536 + 1024 + n] = f2b(v);
  }
};

// final: fp32 out[(y*8+b)*1024 + n] + bias
struct EpiOut {
  float* out; const float* bias;
  __device__ void operator()(int bz, int m, int n, float v) const {
    out[(long)m * 1024 + n] = v + bias[n];
  }
};

// ---------------- generic A x B^T bf16-MFMA GEMM ----------------------------
// A: M x K (lda), B: N x K (ldb); TA/TB in {float, short(bf16 bits)}.
// Tile 64x64, BK=32, 256 threads = 4 waves in 2x2 grid of 32x32 per-wave tiles.
template <typename TA, typename TB, typename Epi>
__global__ __launch_bounds__(256) void gemm_bt(
    const TA* __restrict__ A, long strideAb, int lda,
    const TB* __restrict__ B, long strideBb, int ldb,
    int K, Epi epi) {
  __shared__ short As[64][32];
  __shared__ short Bs[64][32];

  const int tid = threadIdx.x;
  const int bz = blockIdx.z;
  const int m0 = blockIdx.x * 64;
  const int n0 = blockIdx.y * 64;

  const int srow = tid >> 2;         // 0..63
  const int scol = (tid & 3) * 8;    // 0,8,16,24
  const TA* Ap = A + (long)bz * strideAb + (long)(m0 + srow) * lda + scol;
  const TB* Bp = B + (long)bz * strideBb + (long)(n0 + srow) * ldb + scol;

  const int wave = tid >> 6, lane = tid & 63;
  const int wm = (wave & 1) * 32, wn = (wave >> 1) * 32;
  const int quad = lane >> 4, l16 = lane & 15;

  f32x4 acc[2][2] = {};

  for (int k0 = 0; k0 < K; k0 += 32) {
    // ---- stage 64x32 A and B tiles into LDS as bf16 (16B per thread each)
    union { short s[8]; int4 v; } pa, pb;
    if constexpr (sizeof(TA) == 4) {
      float4 f0 = *(const float4*)(Ap + k0);
      float4 f1 = *(const float4*)(Ap + k0 + 4);
      pa.s[0] = f2b(f0.x); pa.s[1] = f2b(f0.y); pa.s[2] = f2b(f0.z); pa.s[3] = f2b(f0.w);
      pa.s[4] = f2b(f1.x); pa.s[5] = f2b(f1.y); pa.s[6] = f2b(f1.z); pa.s[7] = f2b(f1.w);
    } else {
      pa.v = *(const int4*)(Ap + k0);
    }
    if constexpr (sizeof(TB) == 4) {
      float4 f0 = *(const float4*)(Bp + k0);
      float4 f1 = *(const float4*)(Bp + k0 + 4);
      pb.s[0] = f2b(f0.x); pb.s[1] = f2b(f0.y); pb.s[2] = f2b(f0.z); pb.s[3] = f2b(f0.w);
      pb.s[4] = f2b(f1.x); pb.s[5] = f2b(f1.y); pb.s[6] = f2b(f1.z); pb.s[7] = f2b(f1.w);
    } else {
      pb.v = *(const int4*)(Bp + k0);
    }
    *(int4*)(&As[srow][scol]) = pa.v;
    *(int4*)(&Bs[srow][scol]) = pb.v;
    __syncthreads();

    // ---- fragments + 4 MFMAs
    union { int4 v; bf16x8 f; } a0, a1, b0, b1;
    a0.v = *(const int4*)(&As[wm + l16][quad * 8]);
    a1.v = *(const int4*)(&As[wm + 16 + l16][quad * 8]);
    b0.v = *(const int4*)(&Bs[wn + l16][quad * 8]);
    b1.v = *(const int4*)(&Bs[wn + 16 + l16][quad * 8]);
    acc[0][0] = __builtin_amdgcn_mfma_f32_16x16x32_bf16(a0.f, b0.f, acc[0][0], 0, 0, 0);
    acc[0][1] = __builtin_amdgcn_mfma_f32_16x16x32_bf16(a0.f, b1.f, acc[0][1], 0, 0, 0);
    acc[1][0] = __builtin_amdgcn_mfma_f32_16x16x32_bf16(a1.f, b0.f, acc[1][0], 0, 0, 0);
    acc[1][1] = __builtin_amdgcn_mfma_f32_16x16x32_bf16(a1.f, b1.f, acc[1][1], 0, 0, 0);
    __syncthreads();
  }

  // ---- epilogue: C/D layout row=quad*4+reg, col=lane&15
#pragma unroll
  for (int i = 0; i < 2; i++)
#pragma unroll
    for (int j = 0; j < 2; j++)
#pragma unroll
      for (int r = 0; r < 4; r++)
        epi(bz, m0 + wm + i * 16 + quad * 4 + r, n0 + wn + j * 16 + l16,
            acc[i][j][r]);
}

// ---------------- softmax over rows of 2048 (in-place bf16) -----------------
__global__ __launch_bounds__(256) void softmax_rows(short* logits) {
  const long row = blockIdx.x;
  short* p = logits + row * 2048;
  const int tid = threadIdx.x;

  union { short s[8]; int4 v; } d;
  d.v = *(const int4*)(p + tid * 8);
  float vals[8];
  float mx = -FMAXF;
#pragma unroll
  for (int i = 0; i < 8; i++) { vals[i] = b2f(d.s[i]); mx = fmaxf(mx, vals[i]); }
#pragma unroll
  for (int off = 32; off; off >>= 1) mx = fmaxf(mx, __shfl_xor(mx, off));
  __shared__ float redm[4], reds[4];
  if ((tid & 63) == 0) redm[tid >> 6] = mx;
  __syncthreads();
  mx = fmaxf(fmaxf(redm[0], redm[1]), fmaxf(redm[2], redm[3]));

  float s = 0.0f;
#pragma unroll
  for (int i = 0; i < 8; i++) { vals[i] = __expf(vals[i] - mx); s += vals[i]; }
#pragma unroll
  for (int off = 32; off; off >>= 1) s += __shfl_xor(s, off);
  if ((tid & 63) == 0) reds[tid >> 6] = s;
  __syncthreads();
  s = reds[0] + reds[1] + reds[2] + reds[3];
  float inv = 1.0f / s;
#pragma unroll
  for (int i = 0; i < 8; i++) d.s[i] = f2b(vals[i] * inv);
  *(int4*)(p + tid * 8) = d.v;
}

// ---------------- Y (fp32, ld 1024) -> concat[:, :1024] (bf16, ld 1536) -----
__global__ __launch_bounds__(256) void cvt_y_concat(const float* __restrict__ in,
                                                    short* __restrict__ out) {
  long idx = (long)blockIdx.x * 256 + threadIdx.x;  // 8192*256 threads, 4 el each
  long row = idx >> 8;
  int c = (int)(idx & 255) << 2;
  float4 f = *(const float4*)(in + row * 1024 + c);
  union { short s[4]; unsigned long long v; } o;
  o.s[0] = f2b(f.x); o.s[1] = f2b(f.y); o.s[2] = f2b(f.z); o.s[3] = f2b(f.w);
  *(unsigned long long*)(out + row * 1536 + c) = o.v;
}

// ---------------------------------------------------------------------------

extern "C" void kernel_launch(void* const* d_in, const int* in_sizes, int n_in,
                              void* d_out, int out_size, void* d_ws, size_t ws_size,
                              hipStream_t stream) {
  const float* X    = (const float*)d_in[0];
  const float* Y    = (const float*)d_in[1];
  const float* alig = (const float*)d_in[2];
  const int*   mask = (const int*)d_in[3];
  const float* Xk_w = (const float*)d_in[4];
  const float* Xk_b = (const float*)d_in[5];
  const float* Xv_w = (const float*)d_in[6];
  const float* Xv_b = (const float*)d_in[7];
  const float* Yq_w = (const float*)d_in[8];
  const float* Yq_b = (const float*)d_in[9];
  const float* Yw_w = (const float*)d_in[10];
  const float* Yw_b = (const float*)d_in[11];
  const float* alw  = (const float*)d_in[12];
  float* out = (float*)d_out;

  char* ws = (char*)d_ws;
  short* yq     = (short*)(ws + 0);          //  8 MB  [8][1024][512]
  short* xk     = (short*)(ws + 8388608);    // 16 MB  [8][2048][512]
  short* xvt    = (short*)(ws + 25165824);   // 16 MB  [8][512][2048]
  short* logits = (short*)(ws + 41943040);   // 32 MB  [8][1024][2048] (attn in-place)
  short* concat = (short*)(ws + 75497472);   // 24 MB  [8192][1536]

  // Y -> concat[:, :1024]
  cvt_y_concat<<<8192, 256, 0, stream>>>(Y, concat);

  // projections: A=fp32, B=fp32 weights (N x K row-major)
  gemm_bt<float, float, EpiSplitBXD><<<dim3(256, 8, 1), 256, 0, stream>>>(
      X, 0, 1024, Xk_w, 0, 1024, 1024, EpiSplitBXD{xk, Xk_b, 2048});
  gemm_bt<float, float, EpiXvt><<<dim3(256, 8, 1), 256, 0, stream>>>(
      X, 0, 1024, Xv_w, 0, 1024, 1024, EpiXvt{xvt, Xv_b});
  gemm_bt<float, float, EpiSplitBXD><<<dim3(128, 8, 1), 256, 0, stream>>>(
      Y, 0, 1024, Yq_w, 0, 1024, 1024, EpiSplitBXD{yq, Yq_b, 1024});

  // logits: per-batch yq (1024x512) x xk^T (2048x512)
  gemm_bt<short, short, EpiLogit><<<dim3(16, 32, 8), 256, 0, stream>>>(
      yq, (long)1024 * 512, 512, xk, (long)2048 * 512, 512, 512,
      EpiLogit{logits, alig, mask, alw});

  // softmax over x (rows of 2048), in-place bf16
  softmax_rows<<<8192, 256, 0, stream>>>(logits);

  // attn (1024x2048) x xvt^T (512x2048) -> concat[:, 1024:]
  gemm_bt<short, short, EpiConcat><<<dim3(16, 8, 8), 256, 0, stream>>>(
      logits, (long)1024 * 2048, 2048, xvt, (long)512 * 2048, 2048, 2048,
      EpiConcat{concat});

  // final: concat (8192x1536) x Yw_w^T (1024x1536) -> fp32 out
  gemm_bt<short, float, EpiOut><<<dim3(128, 16, 1), 256, 0, stream>>>(
      concat, 0, 1536, Yw_w, 0, 1536, 1536, EpiOut{out, Yw_b});
}

// Round 2
// 482.701 us; speedup vs baseline: 1.2152x; 1.2152x over previous
//
#include <hip/hip_runtime.h>

// ---------------------------------------------------------------------------
// SHCA round 2: m97-structure GEMMs (128x128 tile, BK=32, global_load_lds w16)
// All GEMMs bf16 MFMA 16x16x32, A x B^T, both operands K-contiguous.
// Pipeline:
//   cvt X->xbf, Y->concat[:, :1024], weights->bf16 (Xk|Xv stacked)
//   proj fused:  xbf @ wkv^T  -> xk[b][x][h], xv[b][x][h]
//   yq:          concat @ wyq^T -> yq[b][y][h]
//   transpose:   xv -> xvt[b][h][x]
//   logits:      yq @ xk^T (+scale, gated alignment, mask) -> logits bf16
//   softmax rows of 2048 (in-place)
//   attn@xv:     logits @ xvt^T -> concat[:, 1024:]
//   final:       concat @ wyw^T + b -> out fp32
// ---------------------------------------------------------------------------

#define FMAXF 3.402823466e38f

typedef __attribute__((ext_vector_type(8))) __bf16 bf16x8;
typedef __attribute__((ext_vector_type(4))) float f32x4;

static __device__ __forceinline__ short f2b(float f) {
  union { float f; unsigned u; } x; x.f = f;
  unsigned r = (x.u + 0x7FFFu + ((x.u >> 16) & 1u)) >> 16;
  return (short)r;
}
static __device__ __forceinline__ float b2f(short s) {
  union { unsigned u; float f; } x; x.u = ((unsigned)(unsigned short)s) << 16;
  return x.f;
}

static __device__ __forceinline__ void gl_lds16(const short* g, short* l) {
  __builtin_amdgcn_global_load_lds(
      (const __attribute__((address_space(1))) void*)g,
      (__attribute__((address_space(3))) void*)l, 16, 0, 0);
}

// ---------------- epilogue functors -----------------------------------------

// fused projection: n<512 -> xk[b][x][n], n>=512 -> xv[b][x][n-512]; m = x*8+b
struct EpiKV {
  short* xk; short* xv; const float* kb; const float* vb;
  __device__ void operator()(int bz, int m, int n, float v) const {
    int b = m & 7; long x = m >> 3;
    if (n < 512) {
      xk[((long)b * 2048 + x) * 512 + n] = f2b(v + kb[n]);
    } else {
      xv[((long)b * 2048 + x) * 512 + (n - 512)] = f2b(v + vb[n - 512]);
    }
  }
};

// yq[b][y][n]; m = y*8+b
struct EpiYq {
  short* out; const float* bias;
  __device__ void operator()(int bz, int m, int n, float v) const {
    out[(((long)(m & 7)) * 1024 + (m >> 3)) * 512 + n] = f2b(v + bias[n]);
  }
};

// logits: scale, gated alignment, pad-mask fill; bf16 store [b][y][x]
struct EpiLogit {
  short* out; const float* align; const int* mask; const float* alw;
  __device__ void operator()(int bz, int m, int n, float v) const {
    long idx = ((long)bz * 1024 + m) * 2048 + n;
    float g = 1.0f / (1.0f + __expf(-alw[0]));
    v = v * 0.04419417382415922f + g * align[idx];   // 1/sqrt(512)
    if (mask[idx]) v = -FMAXF;                        // rounds to -inf in bf16, ok
    out[idx] = f2b(v);
  }
};

// attn_feat -> concat[(m*8+bz)][1024+n]
struct EpiConcat {
  short* out;
  __device__ void operator()(int bz, int m, int n, float v) const {
    out[((long)m * 8 + bz) * 1536 + 1024 + n] = f2b(v);
  }
};

// final fp32 out
struct EpiOut {
  float* out; const float* bias;
  __device__ void operator()(int bz, int m, int n, float v) const {
    out[(long)m * 1024 + n] = v + bias[n];
  }
};

// ---------------- 128x128 bf16 MFMA GEMM (A x B^T), global_load_lds --------
// 256 threads = 4 waves (2x2), each wave 64x64 = 4x4 mfma_16x16x32.
template <typename Epi>
__global__ __launch_bounds__(256) void gemm128(
    const short* __restrict__ A, long sAb, int lda,
    const short* __restrict__ B, long sBb, int ldb,
    int K, Epi epi) {
  __shared__ short As[128 * 32];
  __shared__ short Bs[128 * 32];

  const int tid = threadIdx.x;
  const int lane = tid & 63, wave = tid >> 6;
  const int bz = blockIdx.z;
  const int m0 = blockIdx.x * 128;
  const int n0 = blockIdx.y * 128;

  // staging: wave w loads rows [w*32, w*32+32) of both tiles, 2 issues each
  const int rr = lane >> 2;          // row within 16-row chunk
  const int cc = (lane & 3) * 8;     // element column 0,8,16,24
  const int row0 = wave * 32;
  const short* Ag0 = A + (long)bz * sAb + (long)(m0 + row0 + rr) * lda + cc;
  const short* Ag1 = Ag0 + (long)16 * lda;
  const short* Bg0 = B + (long)bz * sBb + (long)(n0 + row0 + rr) * ldb + cc;
  const short* Bg1 = Bg0 + (long)16 * ldb;
  short* Al0 = As + row0 * 32;       // wave-uniform LDS bases
  short* Al1 = As + (row0 + 16) * 32;
  short* Bl0 = Bs + row0 * 32;
  short* Bl1 = Bs + (row0 + 16) * 32;

  const int wm = (wave & 1) * 64, wn = (wave >> 1) * 64;
  const int quad = lane >> 4, l16 = lane & 15;

  f32x4 acc[4][4] = {};

  for (int k0 = 0; k0 < K; k0 += 32) {
    gl_lds16(Ag0 + k0, Al0);
    gl_lds16(Ag1 + k0, Al1);
    gl_lds16(Bg0 + k0, Bl0);
    gl_lds16(Bg1 + k0, Bl1);
    __syncthreads();   // drains vmcnt -> LDS tiles visible

    union { int4 v; bf16x8 f; } a[4], b[4];
#pragma unroll
    for (int i = 0; i < 4; i++) {
      a[i].v = *(const int4*)(As + (wm + i * 16 + l16) * 32 + quad * 8);
      b[i].v = *(const int4*)(Bs + (wn + i * 16 + l16) * 32 + quad * 8);
    }
#pragma unroll
    for (int i = 0; i < 4; i++)
#pragma unroll
      for (int j = 0; j < 4; j++)
        acc[i][j] = __builtin_amdgcn_mfma_f32_16x16x32_bf16(a[i].f, b[j].f,
                                                            acc[i][j], 0, 0, 0);
    __syncthreads();   // tiles consumed; safe to overwrite next iter
  }

  // C/D layout: row = quad*4 + reg, col = lane&15
#pragma unroll
  for (int i = 0; i < 4; i++)
#pragma unroll
    for (int j = 0; j < 4; j++)
#pragma unroll
      for (int r = 0; r < 4; r++)
        epi(bz, m0 + wm + i * 16 + quad * 4 + r, n0 + wn + j * 16 + l16,
            acc[i][j][r]);
}

// ---------------- fp32 -> bf16 flat convert ---------------------------------
__global__ __launch_bounds__(256) void cvt_f32_bf16(const float* __restrict__ in,
                                                    short* __restrict__ out,
                                                    long n4) {
  long i = (long)blockIdx.x * 256 + threadIdx.x;
  if (i >= n4) return;
  float4 f = ((const float4*)in)[i];
  union { short s[4]; long long v; } o;
  o.s[0] = f2b(f.x); o.s[1] = f2b(f.y); o.s[2] = f2b(f.z); o.s[3] = f2b(f.w);
  ((long long*)out)[i] = o.v;
}

// ---------------- Y (fp32, ld 1024) -> concat[:, :1024] (bf16, ld 1536) -----
__global__ __launch_bounds__(256) void cvt_y_concat(const float* __restrict__ in,
                                                    short* __restrict__ out) {
  long idx = (long)blockIdx.x * 256 + threadIdx.x;
  long row = idx >> 8;
  int c = (int)(idx & 255) << 2;
  float4 f = *(const float4*)(in + row * 1024 + c);
  union { short s[4]; unsigned long long v; } o;
  o.s[0] = f2b(f.x); o.s[1] = f2b(f.y); o.s[2] = f2b(f.z); o.s[3] = f2b(f.w);
  *(unsigned long long*)(out + row * 1536 + c) = o.v;
}

// ---------------- xv[b][x][h] -> xvt[b][h][x] (32x32 LDS tiles) -------------
__global__ __launch_bounds__(256) void transpose_xv(const short* __restrict__ xv,
                                                    short* __restrict__ xvt) {
  __shared__ short t[32][36];  // 72B rows: 8B-aligned stores, bank spread
  const int b = blockIdx.z;
  const long x0 = (long)blockIdx.x * 32, h0 = (long)blockIdx.y * 32;
  const int r = threadIdx.x >> 3, c = (threadIdx.x & 7) * 4;
  const short* src = xv + ((long)b * 2048 + x0 + r) * 512 + h0 + c;
  *(int2*)&t[r][c] = *(const int2*)src;
  __syncthreads();
  union { short s[4]; int2 v; } o;
  o.s[0] = t[c + 0][r]; o.s[1] = t[c + 1][r];
  o.s[2] = t[c + 2][r]; o.s[3] = t[c + 3][r];
  short* dst = xvt + ((long)b * 512 + h0 + r) * 2048 + x0 + c;
  *(int2*)dst = o.v;
}

// ---------------- softmax over rows of 2048 (in-place bf16) -----------------
__global__ __launch_bounds__(256) void softmax_rows(short* logits) {
  const long row = blockIdx.x;
  short* p = logits + row * 2048;
  const int tid = threadIdx.x;

  union { short s[8]; int4 v; } d;
  d.v = *(const int4*)(p + tid * 8);
  float vals[8];
  float mx = -FMAXF;
#pragma unroll
  for (int i = 0; i < 8; i++) { vals[i] = b2f(d.s[i]); mx = fmaxf(mx, vals[i]); }
#pragma unroll
  for (int off = 32; off; off >>= 1) mx = fmaxf(mx, __shfl_xor(mx, off));
  __shared__ float redm[4], reds[4];
  if ((tid & 63) == 0) redm[tid >> 6] = mx;
  __syncthreads();
  mx = fmaxf(fmaxf(redm[0], redm[1]), fmaxf(redm[2], redm[3]));

  float s = 0.0f;
#pragma unroll
  for (int i = 0; i < 8; i++) { vals[i] = __expf(vals[i] - mx); s += vals[i]; }
#pragma unroll
  for (int off = 32; off; off >>= 1) s += __shfl_xor(s, off);
  if ((tid & 63) == 0) reds[tid >> 6] = s;
  __syncthreads();
  s = reds[0] + reds[1] + reds[2] + reds[3];
  float inv = 1.0f / s;
#pragma unroll
  for (int i = 0; i < 8; i++) d.s[i] = f2b(vals[i] * inv);
  *(int4*)(p + tid * 8) = d.v;
}

// ---------------------------------------------------------------------------

extern "C" void kernel_launch(void* const* d_in, const int* in_sizes, int n_in,
                              void* d_out, int out_size, void* d_ws, size_t ws_size,
                              hipStream_t stream) {
  const float* X    = (const float*)d_in[0];
  const float* Y    = (const float*)d_in[1];
  const float* alig = (const float*)d_in[2];
  const int*   mask = (const int*)d_in[3];
  const float* Xk_w = (const float*)d_in[4];
  const float* Xk_b = (const float*)d_in[5];
  const float* Xv_w = (const float*)d_in[6];
  const float* Xv_b = (const float*)d_in[7];
  const float* Yq_w = (const float*)d_in[8];
  const float* Yq_b = (const float*)d_in[9];
  const float* Yw_w = (const float*)d_in[10];
  const float* Yw_b = (const float*)d_in[11];
  const float* alw  = (const float*)d_in[12];
  float* out = (float*)d_out;

  char* ws = (char*)d_ws;
  // region 0 (33.5MB): xbf for projections, then reused as logits/attn
  short* xbf    = (short*)(ws + 0);
  short* logits = (short*)(ws + 0);
  short* xk     = (short*)(ws + 33554432);   // 16.8MB [8][2048][512]
  short* xv     = (short*)(ws + 50331648);   // 16.8MB [8][2048][512]
  short* xvt    = (short*)(ws + 67108864);   // 16.8MB [8][512][2048]
  short* yq     = (short*)(ws + 83886080);   //  8.4MB [8][1024][512]
  short* concat = (short*)(ws + 92274688);   // 25.2MB [8192][1536]
  short* wkv    = (short*)(ws + 117440512);  //  2.1MB [1024][1024] (Xk|Xv)
  short* wyq    = (short*)(ws + 119537664);  //  1.0MB [512][1024]
  short* wyw    = (short*)(ws + 120586240);  //  3.1MB [1024][1536]

  // --- converts ---
  cvt_f32_bf16<<<16384, 256, 0, stream>>>(X, xbf, 4194304);          // X 16.7M el
  cvt_y_concat<<<8192, 256, 0, stream>>>(Y, concat);
  cvt_f32_bf16<<<512, 256, 0, stream>>>(Xk_w, wkv, 131072);
  cvt_f32_bf16<<<512, 256, 0, stream>>>(Xv_w, wkv + 512 * 1024, 131072);
  cvt_f32_bf16<<<512, 256, 0, stream>>>(Yq_w, wyq, 131072);
  cvt_f32_bf16<<<1536, 256, 0, stream>>>(Yw_w, wyw, 393216);

  // --- fused xk/xv projection: (16384 x 1024) x (1024 x 1024)^T ---
  gemm128<EpiKV><<<dim3(128, 8, 1), 256, 0, stream>>>(
      xbf, 0, 1024, wkv, 0, 1024, 1024, EpiKV{xk, xv, Xk_b, Xv_b});

  // --- yq: concat[:, :1024] (8192 x 1024, ld 1536) x (512 x 1024)^T ---
  gemm128<EpiYq><<<dim3(64, 4, 1), 256, 0, stream>>>(
      concat, 0, 1536, wyq, 0, 1024, 1024, EpiYq{yq, Yq_b});

  // --- xv -> xvt ---
  transpose_xv<<<dim3(64, 16, 8), 256, 0, stream>>>(xv, xvt);

  // --- logits: per-batch yq (1024x512) x xk^T (2048x512) ---
  gemm128<EpiLogit><<<dim3(8, 16, 8), 256, 0, stream>>>(
      yq, (long)1024 * 512, 512, xk, (long)2048 * 512, 512, 512,
      EpiLogit{logits, alig, mask, alw});

  // --- softmax over x ---
  softmax_rows<<<8192, 256, 0, stream>>>(logits);

  // --- attn @ xv: (1024x2048) x (512x2048)^T -> concat[:, 1024:] ---
  gemm128<EpiConcat><<<dim3(8, 4, 8), 256, 0, stream>>>(
      logits, (long)1024 * 2048, 2048, xvt, (long)512 * 2048, 2048, 2048,
      EpiConcat{concat});

  // --- final: (8192x1536) x (1024x1536)^T -> fp32 out ---
  gemm128<EpiOut><<<dim3(64, 8, 1), 256, 0, stream>>>(
      concat, 0, 1536, wyw, 0, 1536, 1536, EpiOut{out, Yw_b});
}

// Round 3
// 459.355 us; speedup vs baseline: 1.2770x; 1.0508x over previous
//
#include <hip/hip_runtime.h>

// ---------------------------------------------------------------------------
// SHCA round 3:
//  - unified gemm<TM> (TM=128: 2x2 waves of 64x64; TM=64: 1x4 waves of 64x32)
//  - XCD-aware swizzle: blocks sharing an A row-block map to the same XCD
//    (id%8) within a small id window -> A fetched once per XCD.
//  - logits GEMM stores RAW scores; scale + gated alignment + mask moved into
//    the softmax pass (coalesced vector reads there).
// ---------------------------------------------------------------------------

#define FMAXF 3.402823466e38f

typedef __attribute__((ext_vector_type(8))) __bf16 bf16x8;
typedef __attribute__((ext_vector_type(4))) float f32x4;

static __device__ __forceinline__ short f2b(float f) {
  union { float f; unsigned u; } x; x.f = f;
  unsigned r = (x.u + 0x7FFFu + ((x.u >> 16) & 1u)) >> 16;
  return (short)r;
}
static __device__ __forceinline__ float b2f(short s) {
  union { unsigned u; float f; } x; x.u = ((unsigned)(unsigned short)s) << 16;
  return x.f;
}

static __device__ __forceinline__ void gl_lds16(const short* g, short* l) {
  __builtin_amdgcn_global_load_lds(
      (const __attribute__((address_space(1))) void*)g,
      (__attribute__((address_space(3))) void*)l, 16, 0, 0);
}

// ---------------- epilogue functors -----------------------------------------

// fused projection: n<512 -> xk[b][x][n], else xv[b][x][n-512]; m = x*8+b
struct EpiKV {
  short* xk; short* xv; const float* kb; const float* vb;
  __device__ void operator()(int bz, int m, int n, float v) const {
    int b = m & 7; long x = m >> 3;
    if (n < 512) {
      xk[((long)b * 2048 + x) * 512 + n] = f2b(v + kb[n]);
    } else {
      xv[((long)b * 2048 + x) * 512 + (n - 512)] = f2b(v + vb[n - 512]);
    }
  }
};

// yq[b][y][n]; m = y*8+b
struct EpiYq {
  short* out; const float* bias;
  __device__ void operator()(int bz, int m, int n, float v) const {
    out[(((long)(m & 7)) * 1024 + (m >> 3)) * 512 + n] = f2b(v + bias[n]);
  }
};

// raw scores bf16 [b][y][x]
struct EpiLogit {
  short* out;
  __device__ void operator()(int bz, int m, int n, float v) const {
    out[((long)bz * 1024 + m) * 2048 + n] = f2b(v);
  }
};

// attn_feat -> concat[(m*8+bz)][1024+n]
struct EpiConcat {
  short* out;
  __device__ void operator()(int bz, int m, int n, float v) const {
    out[((long)m * 8 + bz) * 1536 + 1024 + n] = f2b(v);
  }
};

// final fp32 out
struct EpiOut {
  float* out; const float* bias;
  __device__ void operator()(int bz, int m, int n, float v) const {
    out[(long)m * 1024 + n] = v + bias[n];
  }
};

// ---------------- TM x 128 bf16 MFMA GEMM (A x B^T) -------------------------
// 256 threads. TM=128: 4 waves 2x2, wave tile 64x64 (4x4 mfma).
//              TM=64 : 4 waves 1x4, wave tile 64x32 (4x2 mfma).
// Block swizzle: id&7 selects XCD-stable m-subtile; blocks sharing A rows
// have identical id%8 and consecutive (id>>3) -> same XCD, same time window.
template <int TM, typename Epi>
__global__ __launch_bounds__(256) void gemm_mt(
    const short* __restrict__ A, long sAb, int lda,
    const short* __restrict__ B, long sBb, int ldb,
    int K, int tlog, Epi epi) {
  constexpr int R = TM + 128;          // total staged rows (A then B)
  constexpr int SEGS = R / 64;         // 16B segments per thread
  __shared__ short S[R * 32];

  const int tid = threadIdx.x;
  const int lane = tid & 63, wave = tid >> 6;
  const int bz = blockIdx.z;

  const int id = blockIdx.x;
  const int xcd = id & 7;
  const int r = id >> 3;
  const int n0 = (r & ((1 << tlog) - 1)) * 128;
  const int m0 = (((r >> tlog) << 3) + xcd) * TM;

  // staging pointers: seg = t*256 + tid; row = seg>>2, col = (seg&3)*8
  const short* gp[SEGS];
#pragma unroll
  for (int t = 0; t < SEGS; t++) {
    int seg = t * 256 + tid;
    int row = seg >> 2, col = (seg & 3) * 8;
    gp[t] = (row < TM)
                ? A + (long)bz * sAb + (long)(m0 + row) * lda + col
                : B + (long)bz * sBb + (long)(n0 + row - TM) * ldb + col;
  }

  const int wm = (TM == 128) ? (wave & 1) * 64 : 0;
  const int wn = (TM == 128) ? (wave >> 1) * 64 : wave * 32;
  constexpr int MI = 4;
  constexpr int MJ = (TM == 128) ? 4 : 2;
  const int quad = lane >> 4, l16 = lane & 15;

  f32x4 acc[MI][MJ] = {};

  for (int k0 = 0; k0 < K; k0 += 32) {
#pragma unroll
    for (int t = 0; t < SEGS; t++)
      gl_lds16(gp[t] + k0, S + (t * 256 + tid) * 8);
    __syncthreads();

    union { int4 v; bf16x8 f; } a[MI], b[MJ];
#pragma unroll
    for (int i = 0; i < MI; i++)
      a[i].v = *(const int4*)(S + (wm + i * 16 + l16) * 32 + quad * 8);
#pragma unroll
    for (int j = 0; j < MJ; j++)
      b[j].v = *(const int4*)(S + (TM + wn + j * 16 + l16) * 32 + quad * 8);
#pragma unroll
    for (int i = 0; i < MI; i++)
#pragma unroll
      for (int j = 0; j < MJ; j++)
        acc[i][j] = __builtin_amdgcn_mfma_f32_16x16x32_bf16(a[i].f, b[j].f,
                                                            acc[i][j], 0, 0, 0);
    __syncthreads();
  }

  // C/D layout: row = quad*4 + reg, col = lane&15
#pragma unroll
  for (int i = 0; i < MI; i++)
#pragma unroll
    for (int j = 0; j < MJ; j++)
#pragma unroll
      for (int r4 = 0; r4 < 4; r4++)
        epi(bz, m0 + wm + i * 16 + quad * 4 + r4, n0 + wn + j * 16 + l16,
            acc[i][j][r4]);
}

// ---------------- fp32 -> bf16 flat convert ---------------------------------
__global__ __launch_bounds__(256) void cvt_f32_bf16(const float* __restrict__ in,
                                                    short* __restrict__ out,
                                                    long n4) {
  long i = (long)blockIdx.x * 256 + threadIdx.x;
  if (i >= n4) return;
  float4 f = ((const float4*)in)[i];
  union { short s[4]; long long v; } o;
  o.s[0] = f2b(f.x); o.s[1] = f2b(f.y); o.s[2] = f2b(f.z); o.s[3] = f2b(f.w);
  ((long long*)out)[i] = o.v;
}

// ---------------- Y (fp32, ld 1024) -> concat[:, :1024] (bf16, ld 1536) -----
__global__ __launch_bounds__(256) void cvt_y_concat(const float* __restrict__ in,
                                                    short* __restrict__ out) {
  long idx = (long)blockIdx.x * 256 + threadIdx.x;
  long row = idx >> 8;
  int c = (int)(idx & 255) << 2;
  float4 f = *(const float4*)(in + row * 1024 + c);
  union { short s[4]; unsigned long long v; } o;
  o.s[0] = f2b(f.x); o.s[1] = f2b(f.y); o.s[2] = f2b(f.z); o.s[3] = f2b(f.w);
  *(unsigned long long*)(out + row * 1536 + c) = o.v;
}

// ---------------- xv[b][x][h] -> xvt[b][h][x] (32x32 LDS tiles) -------------
__global__ __launch_bounds__(256) void transpose_xv(const short* __restrict__ xv,
                                                    short* __restrict__ xvt) {
  __shared__ short t[32][36];
  const int b = blockIdx.z;
  const long x0 = (long)blockIdx.x * 32, h0 = (long)blockIdx.y * 32;
  const int r = threadIdx.x >> 3, c = (threadIdx.x & 7) * 4;
  const short* src = xv + ((long)b * 2048 + x0 + r) * 512 + h0 + c;
  *(int2*)&t[r][c] = *(const int2*)src;
  __syncthreads();
  union { short s[4]; int2 v; } o;
  o.s[0] = t[c + 0][r]; o.s[1] = t[c + 1][r];
  o.s[2] = t[c + 2][r]; o.s[3] = t[c + 3][r];
  short* dst = xvt + ((long)b * 512 + h0 + r) * 2048 + x0 + c;
  *(int2*)dst = o.v;
}

// ------- softmax over rows of 2048, fused scale + gated align + mask --------
__global__ __launch_bounds__(256) void softmax_rows(short* __restrict__ logits,
                                                    const float* __restrict__ align,
                                                    const int* __restrict__ mask,
                                                    const float* __restrict__ alw) {
  const long row = blockIdx.x;                 // row = b*1024 + y
  const long base = row * 2048 + threadIdx.x * 8;
  short* p = logits + base;
  const float g = 1.0f / (1.0f + __expf(-alw[0]));
  const float scale = 0.04419417382415922f;    // 1/sqrt(512)

  union { short s[8]; int4 v; } d;
  d.v = *(const int4*)p;
  float4 al0 = *(const float4*)(align + base);
  float4 al1 = *(const float4*)(align + base + 4);
  int4 mk0 = *(const int4*)(mask + base);
  int4 mk1 = *(const int4*)(mask + base + 4);

  float vals[8];
  vals[0] = mk0.x ? -FMAXF : b2f(d.s[0]) * scale + g * al0.x;
  vals[1] = mk0.y ? -FMAXF : b2f(d.s[1]) * scale + g * al0.y;
  vals[2] = mk0.z ? -FMAXF : b2f(d.s[2]) * scale + g * al0.z;
  vals[3] = mk0.w ? -FMAXF : b2f(d.s[3]) * scale + g * al0.w;
  vals[4] = mk1.x ? -FMAXF : b2f(d.s[4]) * scale + g * al1.x;
  vals[5] = mk1.y ? -FMAXF : b2f(d.s[5]) * scale + g * al1.y;
  vals[6] = mk1.z ? -FMAXF : b2f(d.s[6]) * scale + g * al1.z;
  vals[7] = mk1.w ? -FMAXF : b2f(d.s[7]) * scale + g * al1.w;

  float mx = -FMAXF;
#pragma unroll
  for (int i = 0; i < 8; i++) mx = fmaxf(mx, vals[i]);
#pragma unroll
  for (int off = 32; off; off >>= 1) mx = fmaxf(mx, __shfl_xor(mx, off));
  __shared__ float redm[4], reds[4];
  const int tid = threadIdx.x;
  if ((tid & 63) == 0) redm[tid >> 6] = mx;
  __syncthreads();
  mx = fmaxf(fmaxf(redm[0], redm[1]), fmaxf(redm[2], redm[3]));

  float s = 0.0f;
#pragma unroll
  for (int i = 0; i < 8; i++) { vals[i] = __expf(vals[i] - mx); s += vals[i]; }
#pragma unroll
  for (int off = 32; off; off >>= 1) s += __shfl_xor(s, off);
  if ((tid & 63) == 0) reds[tid >> 6] = s;
  __syncthreads();
  s = reds[0] + reds[1] + reds[2] + reds[3];
  float inv = 1.0f / s;
#pragma unroll
  for (int i = 0; i < 8; i++) d.s[i] = f2b(vals[i] * inv);
  *(int4*)p = d.v;
}

// ---------------------------------------------------------------------------

extern "C" void kernel_launch(void* const* d_in, const int* in_sizes, int n_in,
                              void* d_out, int out_size, void* d_ws, size_t ws_size,
                              hipStream_t stream) {
  const float* X    = (const float*)d_in[0];
  const float* Y    = (const float*)d_in[1];
  const float* alig = (const float*)d_in[2];
  const int*   mask = (const int*)d_in[3];
  const float* Xk_w = (const float*)d_in[4];
  const float* Xk_b = (const float*)d_in[5];
  const float* Xv_w = (const float*)d_in[6];
  const float* Xv_b = (const float*)d_in[7];
  const float* Yq_w = (const float*)d_in[8];
  const float* Yq_b = (const float*)d_in[9];
  const float* Yw_w = (const float*)d_in[10];
  const float* Yw_b = (const float*)d_in[11];
  const float* alw  = (const float*)d_in[12];
  float* out = (float*)d_out;

  char* ws = (char*)d_ws;
  short* xbf    = (short*)(ws + 0);          // 33.5MB; reused as logits/attn
  short* logits = (short*)(ws + 0);
  short* xk     = (short*)(ws + 33554432);   // 16.8MB [8][2048][512]
  short* xv     = (short*)(ws + 50331648);   // 16.8MB [8][2048][512]
  short* xvt    = (short*)(ws + 67108864);   // 16.8MB [8][512][2048]
  short* yq     = (short*)(ws + 83886080);   //  8.4MB [8][1024][512]
  short* concat = (short*)(ws + 92274688);   // 25.2MB [8192][1536]
  short* wkv    = (short*)(ws + 117440512);  //  2.1MB [1024][1024] (Xk|Xv)
  short* wyq    = (short*)(ws + 119537664);  //  1.0MB [512][1024]
  short* wyw    = (short*)(ws + 120586240);  //  3.1MB [1024][1536]

  // --- converts ---
  cvt_f32_bf16<<<16384, 256, 0, stream>>>(X, xbf, 4194304);
  cvt_y_concat<<<8192, 256, 0, stream>>>(Y, concat);
  cvt_f32_bf16<<<512, 256, 0, stream>>>(Xk_w, wkv, 131072);
  cvt_f32_bf16<<<512, 256, 0, stream>>>(Xv_w, wkv + 512 * 1024, 131072);
  cvt_f32_bf16<<<512, 256, 0, stream>>>(Yq_w, wyq, 131072);
  cvt_f32_bf16<<<1536, 256, 0, stream>>>(Yw_w, wyw, 393216);

  // --- fused xk/xv projection: (16384 x 1024) x (1024 x 1024)^T ---
  // tilesM=128, tilesN=8 (tlog=3) -> grid 1024
  gemm_mt<128, EpiKV><<<dim3(1024, 1, 1), 256, 0, stream>>>(
      xbf, 0, 1024, wkv, 0, 1024, 1024, 3, EpiKV{xk, xv, Xk_b, Xv_b});

  // --- yq: concat[:, :1024] (8192 x 1024, ld 1536) x (512 x 1024)^T ---
  // TM=64: tilesM=128, tilesN=4 (tlog=2) -> grid 512
  gemm_mt<64, EpiYq><<<dim3(512, 1, 1), 256, 0, stream>>>(
      concat, 0, 1536, wyq, 0, 1024, 1024, 2, EpiYq{yq, Yq_b});

  // --- xv -> xvt ---
  transpose_xv<<<dim3(64, 16, 8), 256, 0, stream>>>(xv, xvt);

  // --- logits (raw): per-batch yq (1024x512) x xk^T (2048x512) ---
  // tilesM=8, tilesN=16 (tlog=4) -> grid 128 x z8
  gemm_mt<128, EpiLogit><<<dim3(128, 1, 8), 256, 0, stream>>>(
      yq, (long)1024 * 512, 512, xk, (long)2048 * 512, 512, 512, 4,
      EpiLogit{logits});

  // --- softmax (fused scale + gated alignment + mask) ---
  softmax_rows<<<8192, 256, 0, stream>>>(logits, alig, mask, alw);

  // --- attn @ xv: (1024x2048) x (512x2048)^T -> concat[:, 1024:] ---
  // TM=64: tilesM=16, tilesN=4 (tlog=2) -> grid 64 x z8
  gemm_mt<64, EpiConcat><<<dim3(64, 1, 8), 256, 0, stream>>>(
      logits, (long)1024 * 2048, 2048, xvt, (long)512 * 2048, 2048, 2048, 2,
      EpiConcat{concat});

  // --- final: (8192x1536) x (1024x1536)^T -> fp32 out ---
  // tilesM=64, tilesN=8 (tlog=3) -> grid 512
  gemm_mt<128, EpiOut><<<dim3(512, 1, 1), 256, 0, stream>>>(
      concat, 0, 1536, wyw, 0, 1536, 1536, 3, EpiOut{out, Yw_b});
}

// Round 4
// 424.740 us; speedup vs baseline: 1.3810x; 1.0815x over previous
//
#include <hip/hip_runtime.h>

// ---------------------------------------------------------------------------
// SHCA round 4:
//  - BK=64 K-loop (half the barriers), XOR-swizzled staging so b128 fragment
//    reads have uniform bank-group distribution (8 lanes x 8 groups).
//  - LDS-staged coalesced epilogue (int4 stores) for bf16-output GEMMs.
//  - fused weight-convert kernel (fewer dispatches).
// ---------------------------------------------------------------------------

#define FMAXF 3.402823466e38f

typedef __attribute__((ext_vector_type(8))) __bf16 bf16x8;
typedef __attribute__((ext_vector_type(4))) float f32x4;

static __device__ __forceinline__ short f2b(float f) {
  union { float f; unsigned u; } x; x.f = f;
  unsigned r = (x.u + 0x7FFFu + ((x.u >> 16) & 1u)) >> 16;
  return (short)r;
}
static __device__ __forceinline__ float b2f(short s) {
  union { unsigned u; float f; } x; x.u = ((unsigned)(unsigned short)s) << 16;
  return x.f;
}

static __device__ __forceinline__ void gl_lds16(const short* g, short* l) {
  __builtin_amdgcn_global_load_lds(
      (const __attribute__((address_space(1))) void*)g,
      (__attribute__((address_space(3))) void*)l, 16, 0, 0);
}

// ---------------- epilogue functors -----------------------------------------
// staged epis: bias_at(n) additive bias; store(bz,m,n,int4) 8-col chunk.

struct EpiKV {
  static constexpr bool staged = true;
  short* xk; short* xv; const float* kb; const float* vb;
  __device__ float bias_at(int n) const { return n < 512 ? kb[n] : vb[n - 512]; }
  __device__ void store(int bz, int m, int n, int4 v) const {
    int b = m & 7; long x = m >> 3;
    if (n < 512) *(int4*)(xk + ((long)b * 2048 + x) * 512 + n) = v;
    else         *(int4*)(xv + ((long)b * 2048 + x) * 512 + (n - 512)) = v;
  }
};

struct EpiYq {
  static constexpr bool staged = true;
  short* out; const float* bias;
  __device__ float bias_at(int n) const { return bias[n]; }
  __device__ void store(int bz, int m, int n, int4 v) const {
    *(int4*)(out + (((long)(m & 7)) * 1024 + (m >> 3)) * 512 + n) = v;
  }
};

struct EpiLogit {
  static constexpr bool staged = true;
  short* out;
  __device__ float bias_at(int n) const { return 0.0f; }
  __device__ void store(int bz, int m, int n, int4 v) const {
    *(int4*)(out + ((long)bz * 1024 + m) * 2048 + n) = v;
  }
};

struct EpiConcat {
  static constexpr bool staged = true;
  short* out;
  __device__ float bias_at(int n) const { return 0.0f; }
  __device__ void store(int bz, int m, int n, int4 v) const {
    *(int4*)(out + ((long)m * 8 + bz) * 1536 + 1024 + n) = v;
  }
};

struct EpiOut {  // fp32 output, direct stores (64B/quad segments)
  static constexpr bool staged = false;
  float* out; const float* bias;
  __device__ void direct(int bz, int m, int n, float v) const {
    out[(long)m * 1024 + n] = v + bias[n];
  }
};

// ---------------- TM x 128 bf16 MFMA GEMM (A x B^T), BK=64 ------------------
// 256 threads. TM=128: 4 waves 2x2 (wave 64x64, 16 mfma/k-step).
//              TM=64 : 4 waves 1x4 (wave 64x32,  8 mfma/k-step).
// Staging: linear gl_lds slots; lane's GLOBAL column granule is XOR-swizzled
// (g ^ (row&7)) so that b128 fragment reads are bank-uniform.
template <int TM, typename Epi>
__global__ __launch_bounds__(256) void gemm_mt(
    const short* __restrict__ A, long sAb, int lda,
    const short* __restrict__ B, long sBb, int ldb,
    int K, int tlog, Epi epi) {
  constexpr int R = TM + 128;           // staged rows (A then B), 128B each
  constexpr int SEGS = R / 32;          // 16B slots per thread
  constexpr int LDSN = (R * 64 > TM * 128) ? R * 64 : TM * 128;
  __shared__ short S[LDSN];

  const int tid = threadIdx.x;
  const int lane = tid & 63, wave = tid >> 6;
  const int bz = blockIdx.z;

  const int id = blockIdx.x;
  const int xcd = id & 7;
  const int rr = id >> 3;
  const int n0 = (rr & ((1 << tlog) - 1)) * 128;
  const int m0 = (((rr >> tlog) << 3) + xcd) * TM;

  // staging pointers: slot = t*256 + tid; row = slot>>3, granule = slot&7
  const short* gp[SEGS];
#pragma unroll
  for (int t = 0; t < SEGS; t++) {
    int slot = t * 256 + tid;
    int row = slot >> 3;
    int gcol = ((slot & 7) ^ (row & 7)) * 8;
    gp[t] = (row < TM)
                ? A + (long)bz * sAb + (long)(m0 + row) * lda + gcol
                : B + (long)bz * sBb + (long)(n0 + row - TM) * ldb + gcol;
  }

  const int wm = (TM == 128) ? (wave & 1) * 64 : 0;
  const int wn = (TM == 128) ? (wave >> 1) * 64 : wave * 32;
  constexpr int MI = 4;
  constexpr int MJ = (TM == 128) ? 4 : 2;
  const int quad = lane >> 4, l16 = lane & 15;
  const int xr = l16 & 7;               // row-XOR for fragment reads

  f32x4 acc[MI][MJ] = {};

  for (int k0 = 0; k0 < K; k0 += 64) {
#pragma unroll
    for (int t = 0; t < SEGS; t++)
      gl_lds16(gp[t] + k0, S + (t * 256 + tid) * 8);
    __syncthreads();

#pragma unroll
    for (int kk = 0; kk < 2; kk++) {
      union { int4 v; bf16x8 f; } a[MI], b[MJ];
      const int g = ((kk << 2) + quad);
#pragma unroll
      for (int i = 0; i < MI; i++)
        a[i].v = *(const int4*)(S + (wm + i * 16 + l16) * 64 + (g ^ xr) * 8);
#pragma unroll
      for (int j = 0; j < MJ; j++)
        b[j].v = *(const int4*)(S + (TM + wn + j * 16 + l16) * 64 + (g ^ xr) * 8);
#pragma unroll
      for (int i = 0; i < MI; i++)
#pragma unroll
        for (int j = 0; j < MJ; j++)
          acc[i][j] = __builtin_amdgcn_mfma_f32_16x16x32_bf16(a[i].f, b[j].f,
                                                              acc[i][j], 0, 0, 0);
    }
    __syncthreads();
  }

  if constexpr (Epi::staged) {
    // stage C tile (TM x 128 bf16) in LDS, then coalesced int4 stores
#pragma unroll
    for (int j = 0; j < MJ; j++) {
      const int c = wn + j * 16 + l16;
      const float bj = epi.bias_at(n0 + c);
#pragma unroll
      for (int i = 0; i < MI; i++)
#pragma unroll
        for (int r = 0; r < 4; r++)
          S[(wm + i * 16 + quad * 4 + r) * 128 + c] = f2b(acc[i][j][r] + bj);
    }
    __syncthreads();
#pragma unroll
    for (int t = 0; t < TM / 16; t++) {
      int c = t * 256 + tid;
      int row = c >> 4, colc = (c & 15) * 8;
      int4 v = *(const int4*)(S + row * 128 + colc);
      epi.store(bz, m0 + row, n0 + colc, v);
    }
  } else {
#pragma unroll
    for (int i = 0; i < MI; i++)
#pragma unroll
      for (int j = 0; j < MJ; j++)
#pragma unroll
        for (int r = 0; r < 4; r++)
          epi.direct(bz, m0 + wm + i * 16 + quad * 4 + r,
                     n0 + wn + j * 16 + l16, acc[i][j][r]);
  }
}

// ---------------- converts --------------------------------------------------
__global__ __launch_bounds__(256) void cvt_f32_bf16(const float* __restrict__ in,
                                                    short* __restrict__ out,
                                                    long n4) {
  long i = (long)blockIdx.x * 256 + threadIdx.x;
  if (i >= n4) return;
  float4 f = ((const float4*)in)[i];
  union { short s[4]; long long v; } o;
  o.s[0] = f2b(f.x); o.s[1] = f2b(f.y); o.s[2] = f2b(f.z); o.s[3] = f2b(f.w);
  ((long long*)out)[i] = o.v;
}

// all 4 weight matrices in one dispatch (ranges in float4 units)
__global__ __launch_bounds__(256) void cvt_weights(
    const float* __restrict__ xk_w, const float* __restrict__ xv_w,
    const float* __restrict__ yq_w, const float* __restrict__ yw_w,
    short* __restrict__ wkv, short* __restrict__ wyq, short* __restrict__ wyw) {
  long i = (long)blockIdx.x * 256 + threadIdx.x;
  const float* src; long long* dst; long off;
  if (i < 131072)      { src = xk_w; dst = (long long*)wkv; off = i; }
  else if (i < 262144) { src = xv_w; dst = (long long*)wkv + 131072; off = i - 131072; }
  else if (i < 393216) { src = yq_w; dst = (long long*)wyq; off = i - 262144; }
  else                 { src = yw_w; dst = (long long*)wyw; off = i - 393216; }
  float4 f = ((const float4*)src)[off];
  union { short s[4]; long long v; } o;
  o.s[0] = f2b(f.x); o.s[1] = f2b(f.y); o.s[2] = f2b(f.z); o.s[3] = f2b(f.w);
  dst[off] = o.v;
}

__global__ __launch_bounds__(256) void cvt_y_concat(const float* __restrict__ in,
                                                    short* __restrict__ out) {
  long idx = (long)blockIdx.x * 256 + threadIdx.x;
  long row = idx >> 8;
  int c = (int)(idx & 255) << 2;
  float4 f = *(const float4*)(in + row * 1024 + c);
  union { short s[4]; unsigned long long v; } o;
  o.s[0] = f2b(f.x); o.s[1] = f2b(f.y); o.s[2] = f2b(f.z); o.s[3] = f2b(f.w);
  *(unsigned long long*)(out + row * 1536 + c) = o.v;
}

// ---------------- xv[b][x][h] -> xvt[b][h][x] (32x32 LDS tiles) -------------
__global__ __launch_bounds__(256) void transpose_xv(const short* __restrict__ xv,
                                                    short* __restrict__ xvt) {
  __shared__ short t[32][36];
  const int b = blockIdx.z;
  const long x0 = (long)blockIdx.x * 32, h0 = (long)blockIdx.y * 32;
  const int r = threadIdx.x >> 3, c = (threadIdx.x & 7) * 4;
  const short* src = xv + ((long)b * 2048 + x0 + r) * 512 + h0 + c;
  *(int2*)&t[r][c] = *(const int2*)src;
  __syncthreads();
  union { short s[4]; int2 v; } o;
  o.s[0] = t[c + 0][r]; o.s[1] = t[c + 1][r];
  o.s[2] = t[c + 2][r]; o.s[3] = t[c + 3][r];
  short* dst = xvt + ((long)b * 512 + h0 + r) * 2048 + x0 + c;
  *(int2*)dst = o.v;
}

// ------- softmax over rows of 2048, fused scale + gated align + mask --------
__global__ __launch_bounds__(256) void softmax_rows(short* __restrict__ logits,
                                                    const float* __restrict__ align,
                                                    const int* __restrict__ mask,
                                                    const float* __restrict__ alw) {
  const long row = blockIdx.x;
  const long base = row * 2048 + threadIdx.x * 8;
  short* p = logits + base;
  const float g = 1.0f / (1.0f + __expf(-alw[0]));
  const float scale = 0.04419417382415922f;    // 1/sqrt(512)

  union { short s[8]; int4 v; } d;
  d.v = *(const int4*)p;
  float4 al0 = *(const float4*)(align + base);
  float4 al1 = *(const float4*)(align + base + 4);
  int4 mk0 = *(const int4*)(mask + base);
  int4 mk1 = *(const int4*)(mask + base + 4);

  float vals[8];
  vals[0] = mk0.x ? -FMAXF : b2f(d.s[0]) * scale + g * al0.x;
  vals[1] = mk0.y ? -FMAXF : b2f(d.s[1]) * scale + g * al0.y;
  vals[2] = mk0.z ? -FMAXF : b2f(d.s[2]) * scale + g * al0.z;
  vals[3] = mk0.w ? -FMAXF : b2f(d.s[3]) * scale + g * al0.w;
  vals[4] = mk1.x ? -FMAXF : b2f(d.s[4]) * scale + g * al1.x;
  vals[5] = mk1.y ? -FMAXF : b2f(d.s[5]) * scale + g * al1.y;
  vals[6] = mk1.z ? -FMAXF : b2f(d.s[6]) * scale + g * al1.z;
  vals[7] = mk1.w ? -FMAXF : b2f(d.s[7]) * scale + g * al1.w;

  float mx = -FMAXF;
#pragma unroll
  for (int i = 0; i < 8; i++) mx = fmaxf(mx, vals[i]);
#pragma unroll
  for (int off = 32; off; off >>= 1) mx = fmaxf(mx, __shfl_xor(mx, off));
  __shared__ float redm[4], reds[4];
  const int tid = threadIdx.x;
  if ((tid & 63) == 0) redm[tid >> 6] = mx;
  __syncthreads();
  mx = fmaxf(fmaxf(redm[0], redm[1]), fmaxf(redm[2], redm[3]));

  float s = 0.0f;
#pragma unroll
  for (int i = 0; i < 8; i++) { vals[i] = __expf(vals[i] - mx); s += vals[i]; }
#pragma unroll
  for (int off = 32; off; off >>= 1) s += __shfl_xor(s, off);
  if ((tid & 63) == 0) reds[tid >> 6] = s;
  __syncthreads();
  s = reds[0] + reds[1] + reds[2] + reds[3];
  float inv = 1.0f / s;
#pragma unroll
  for (int i = 0; i < 8; i++) d.s[i] = f2b(vals[i] * inv);
  *(int4*)p = d.v;
}

// ---------------------------------------------------------------------------

extern "C" void kernel_launch(void* const* d_in, const int* in_sizes, int n_in,
                              void* d_out, int out_size, void* d_ws, size_t ws_size,
                              hipStream_t stream) {
  const float* X    = (const float*)d_in[0];
  const float* Y    = (const float*)d_in[1];
  const float* alig = (const float*)d_in[2];
  const int*   mask = (const int*)d_in[3];
  const float* Xk_w = (const float*)d_in[4];
  const float* Xk_b = (const float*)d_in[5];
  const float* Xv_w = (const float*)d_in[6];
  const float* Xv_b = (const float*)d_in[7];
  const float* Yq_w = (const float*)d_in[8];
  const float* Yq_b = (const float*)d_in[9];
  const float* Yw_w = (const float*)d_in[10];
  const float* Yw_b = (const float*)d_in[11];
  const float* alw  = (const float*)d_in[12];
  float* out = (float*)d_out;

  char* ws = (char*)d_ws;
  short* xbf    = (short*)(ws + 0);          // 33.5MB; reused as logits/attn
  short* logits = (short*)(ws + 0);
  short* xk     = (short*)(ws + 33554432);   // 16.8MB [8][2048][512]
  short* xv     = (short*)(ws + 50331648);   // 16.8MB [8][2048][512]
  short* xvt    = (short*)(ws + 67108864);   // 16.8MB [8][512][2048]
  short* yq     = (short*)(ws + 83886080);   //  8.4MB [8][1024][512]
  short* concat = (short*)(ws + 92274688);   // 25.2MB [8192][1536]
  short* wkv    = (short*)(ws + 117440512);  //  2.1MB [1024][1024] (Xk|Xv)
  short* wyq    = (short*)(ws + 119537664);  //  1.0MB [512][1024]
  short* wyw    = (short*)(ws + 120586240);  //  3.1MB [1024][1536]

  // --- converts (3 dispatches) ---
  cvt_f32_bf16<<<16384, 256, 0, stream>>>(X, xbf, 4194304);
  cvt_y_concat<<<8192, 256, 0, stream>>>(Y, concat);
  cvt_weights<<<3072, 256, 0, stream>>>(Xk_w, Xv_w, Yq_w, Yw_w, wkv, wyq, wyw);

  // --- fused xk/xv projection: (16384 x 1024) x (1024 x 1024)^T ---
  gemm_mt<128, EpiKV><<<dim3(1024, 1, 1), 256, 0, stream>>>(
      xbf, 0, 1024, wkv, 0, 1024, 1024, 3, EpiKV{xk, xv, Xk_b, Xv_b});

  // --- yq: concat[:, :1024] (8192 x 1024, ld 1536) x (512 x 1024)^T ---
  gemm_mt<64, EpiYq><<<dim3(512, 1, 1), 256, 0, stream>>>(
      concat, 0, 1536, wyq, 0, 1024, 1024, 2, EpiYq{yq, Yq_b});

  // --- xv -> xvt ---
  transpose_xv<<<dim3(64, 16, 8), 256, 0, stream>>>(xv, xvt);

  // --- logits (raw): per-batch yq (1024x512) x xk^T (2048x512) ---
  gemm_mt<128, EpiLogit><<<dim3(128, 1, 8), 256, 0, stream>>>(
      yq, (long)1024 * 512, 512, xk, (long)2048 * 512, 512, 512, 4,
      EpiLogit{logits});

  // --- softmax (fused scale + gated alignment + mask) ---
  softmax_rows<<<8192, 256, 0, stream>>>(logits, alig, mask, alw);

  // --- attn @ xv: (1024x2048) x (512x2048)^T -> concat[:, 1024:] ---
  gemm_mt<64, EpiConcat><<<dim3(64, 1, 8), 256, 0, stream>>>(
      logits, (long)1024 * 2048, 2048, xvt, (long)512 * 2048, 2048, 2048, 2,
      EpiConcat{concat});

  // --- final: (8192x1536) x (1024x1536)^T -> fp32 out ---
  gemm_mt<128, EpiOut><<<dim3(512, 1, 1), 256, 0, stream>>>(
      concat, 0, 1536, wyw, 0, 1536, 1536, 3, EpiOut{out, Yw_b});
}